// Round 2
// 450.405 us; speedup vs baseline: 1.0600x; 1.0600x over previous
//
#include <hip/hip_runtime.h>
#include <math.h>

// B=16, C=512, H=W=64, N=4096
#define CCH  512
#define NTOK 4096
#define NB   16
#define KSPL 2048          // split-K half length for energy GEMM
#define LDA  40            // LDS row stride in shorts (80 B: 16B-aligned, breaks pow2 banks)

typedef __attribute__((ext_vector_type(8))) _Float16 h8v;  // 8 fp16 (4 VGPRs)
typedef __attribute__((ext_vector_type(4))) float f4v;     // 4 fp32 acc
typedef unsigned short u16;

// fp32 -> fp16 RNE bits
__device__ __forceinline__ u16 f16bits(float x) {
    _Float16 h = (_Float16)x;
    return __builtin_bit_cast(u16, h);
}
// fp32 -> (hi, lo) fp16 pair, RNE. x ~= hi + lo with rel err ~2^-22.
__device__ __forceinline__ void splith(float x, u16& h, u16& l) {
    _Float16 hh = (_Float16)x;
    float hf = (float)hh;
    _Float16 ll = (_Float16)(x - hf);
    h = __builtin_bit_cast(u16, hh);
    l = __builtin_bit_cast(u16, ll);
}

// ---------------------------------------------------------------------------
// K1: E[s][b][c][d] partial = sum_{k in split s} q[b,c,k] * kv[b,d,k]
// 128x128 tile, BK=32, 16x16x32 f16 MFMA.
// fp16 split: energy ~= (q_h + q_l) . kv_h   (2 products; dropped q_h.l_kv term
// has sigma~0.008 on energies of sigma~64 -> negligible through the near-one-hot
// channel softmax). grid (4,4,32)
// ---------------------------------------------------------------------------
__global__ __launch_bounds__(256, 3)
void energy_mfma(const float* __restrict__ q, const float* __restrict__ kv,
                 float* __restrict__ E) {
    __shared__ short Ah[128 * LDA], Al[128 * LDA], Bh[128 * LDA];
    const int b  = blockIdx.z >> 1;
    const int s  = blockIdx.z & 1;
    const int c0 = blockIdx.y * 128, d0 = blockIdx.x * 128;
    const int tid  = threadIdx.x;
    const int lane = tid & 63, wave = tid >> 6;
    const int wm = wave & 1, wn = wave >> 1;
    const int l15 = lane & 15, quad = lane >> 4;

    const int srow = tid >> 1;          // staged tile row 0..127
    const int skq  = (tid & 1) * 16;    // k offset 0/16
    const float* ga = q  + ((size_t)(b * CCH + c0 + srow)) * NTOK + s * KSPL + skq;
    const float* gb = kv + ((size_t)(b * CCH + d0 + srow)) * NTOK + s * KSPL + skq;

    f4v acc[4][4];
#pragma unroll
    for (int i = 0; i < 4; ++i)
#pragma unroll
        for (int j = 0; j < 4; ++j) acc[i][j] = (f4v)0.f;

    float4 pa[4], pb[4];
#pragma unroll
    for (int i = 0; i < 4; ++i) {
        pa[i] = ((const float4*)ga)[i];
        pb[i] = ((const float4*)gb)[i];
    }

    for (int kc = 0; kc < KSPL; kc += 32) {
        __syncthreads();
#pragma unroll
        for (int i = 0; i < 4; ++i) {
            u16 h0, l0, h1, l1, h2, l2, h3, l3;
            splith(pa[i].x, h0, l0);
            splith(pa[i].y, h1, l1);
            splith(pa[i].z, h2, l2);
            splith(pa[i].w, h3, l3);
            *(ushort4*)&Ah[srow * LDA + skq + i * 4] = make_ushort4(h0, h1, h2, h3);
            *(ushort4*)&Al[srow * LDA + skq + i * 4] = make_ushort4(l0, l1, l2, l3);
            *(ushort4*)&Bh[srow * LDA + skq + i * 4] =
                make_ushort4(f16bits(pb[i].x), f16bits(pb[i].y),
                             f16bits(pb[i].z), f16bits(pb[i].w));
        }
        __syncthreads();
        if (kc + 32 < KSPL) {
            const float* ga2 = ga + kc + 32;
            const float* gb2 = gb + kc + 32;
#pragma unroll
            for (int i = 0; i < 4; ++i) {
                pa[i] = ((const float4*)ga2)[i];
                pb[i] = ((const float4*)gb2)[i];
            }
        }
        const int koff = quad * 8;
        const int abase = (wm * 64 + l15) * LDA + koff;
        const int bbase = (wn * 64 + l15) * LDA + koff;
        h8v a_h[4], a_l[4];
#pragma unroll
        for (int i = 0; i < 4; ++i) {
            a_h[i] = *(const h8v*)&Ah[abase + i * 16 * LDA];
            a_l[i] = *(const h8v*)&Al[abase + i * 16 * LDA];
        }
#pragma unroll
        for (int j = 0; j < 4; ++j) {
            h8v b_h = *(const h8v*)&Bh[bbase + j * 16 * LDA];
#pragma unroll
            for (int i = 0; i < 4; ++i) {
                acc[i][j] = __builtin_amdgcn_mfma_f32_16x16x32_f16(a_h[i], b_h, acc[i][j], 0, 0, 0);
                acc[i][j] = __builtin_amdgcn_mfma_f32_16x16x32_f16(a_l[i], b_h, acc[i][j], 0, 0, 0);
            }
        }
    }

    float* Eb = E + ((size_t)(s * NB + b)) * CCH * CCH;
#pragma unroll
    for (int i = 0; i < 4; ++i)
#pragma unroll
        for (int r = 0; r < 4; ++r) {
            const int row = c0 + wm * 64 + i * 16 + quad * 4 + r;
#pragma unroll
            for (int j = 0; j < 4; ++j)
                Eb[(size_t)row * CCH + d0 + wn * 64 + j * 16 + l15] = acc[i][j][r];
        }
}

// ---------------------------------------------------------------------------
// K2: att = softmax(min - e) over d, e = E0 + E1. Emits att as SINGLE fp16
// (att in [0,1], rel err 2^-12 -- enough since att is near-one-hot).
// ---------------------------------------------------------------------------
__global__ __launch_bounds__(256)
void attn_softmax(const float* __restrict__ E0, const float* __restrict__ E1,
                  u16* __restrict__ ah) {
    __shared__ float red[4];
    const size_t base = (size_t)blockIdx.x * CCH;
    const int t = threadIdx.x;
    float e0 = E0[base + t] + E1[base + t];
    float e1 = E0[base + t + 256] + E1[base + t + 256];
    float m = fminf(e0, e1);
#pragma unroll
    for (int off = 32; off > 0; off >>= 1) m = fminf(m, __shfl_xor(m, off, 64));
    if ((t & 63) == 0) red[t >> 6] = m;
    __syncthreads();
    const float mAll = fminf(fminf(red[0], red[1]), fminf(red[2], red[3]));
    float x0 = __expf(mAll - e0);
    float x1 = __expf(mAll - e1);
    float sum = x0 + x1;
#pragma unroll
    for (int off = 32; off > 0; off >>= 1) sum += __shfl_xor(sum, off, 64);
    __syncthreads();
    if ((t & 63) == 0) red[t >> 6] = sum;
    __syncthreads();
    const float inv = 1.0f / (red[0] + red[1] + red[2] + red[3]);
    ah[base + t]       = f16bits(x0 * inv);
    ah[base + t + 256] = f16bits(x1 * inv);
}

// ---------------------------------------------------------------------------
// K3: out = att (C x C, fp16) * kv (C x N, fp16) -- SINGLE product.
// Fused final softmax over W=64 in the epilogue. grid (32,4,16).
// ---------------------------------------------------------------------------
__global__ __launch_bounds__(256, 3)
void out_mfma(const u16* __restrict__ att, const float* __restrict__ kv,
              float* __restrict__ out) {
    __shared__ short Ah[128 * LDA], Bs[128 * LDA];
    const int b  = blockIdx.z;
    const int c0 = blockIdx.y * 128;
    const int n0 = blockIdx.x * 128;
    const int tid  = threadIdx.x;
    const int lane = tid & 63, wave = tid >> 6;
    const int wm = wave & 1, wn = wave >> 1;
    const int l15 = lane & 15, quad = lane >> 4;

    // A staging map (rows of att, k contiguous) -- already fp16, no conversion
    const int arow = tid >> 1, akq = (tid & 1) * 16;
    const u16* gah = att + ((size_t)(b * CCH + c0 + arow)) * CCH + akq;
    // B staging map (transpose: 128 n-lanes x 16 k each)
    const int bn = tid & 127, bkg = (tid >> 7) * 16;
    const float* gb = kv + (size_t)b * CCH * NTOK + n0 + bn;

    f4v acc[4][4];
#pragma unroll
    for (int i = 0; i < 4; ++i)
#pragma unroll
        for (int j = 0; j < 4; ++j) acc[i][j] = (f4v)0.f;

    ushort4 pah[4];
    float pbf[16];
#pragma unroll
    for (int i = 0; i < 4; ++i) pah[i] = *(const ushort4*)(gah + i * 4);
#pragma unroll
    for (int t = 0; t < 16; ++t) pbf[t] = gb[(size_t)(bkg + t) * NTOK];

    for (int kc = 0; kc < CCH; kc += 32) {
        __syncthreads();
#pragma unroll
        for (int i = 0; i < 4; ++i)
            *(ushort4*)&Ah[arow * LDA + akq + i * 4] = pah[i];
#pragma unroll
        for (int p = 0; p < 4; ++p) {
            ushort4 v = make_ushort4(f16bits(pbf[p * 4 + 0]), f16bits(pbf[p * 4 + 1]),
                                     f16bits(pbf[p * 4 + 2]), f16bits(pbf[p * 4 + 3]));
            *(ushort4*)&Bs[bn * LDA + bkg + p * 4] = v;
        }
        __syncthreads();
        if (kc + 32 < CCH) {
#pragma unroll
            for (int i = 0; i < 4; ++i)
                pah[i] = *(const ushort4*)(gah + kc + 32 + i * 4);
#pragma unroll
            for (int t = 0; t < 16; ++t) pbf[t] = gb[(size_t)(kc + 32 + bkg + t) * NTOK];
        }
        const int koff = quad * 8;
        const int abase = (wm * 64 + l15) * LDA + koff;
        const int bbase = (wn * 64 + l15) * LDA + koff;
        h8v a_h[4];
#pragma unroll
        for (int i = 0; i < 4; ++i)
            a_h[i] = *(const h8v*)&Ah[abase + i * 16 * LDA];
#pragma unroll
        for (int j = 0; j < 4; ++j) {
            h8v bb = *(const h8v*)&Bs[bbase + j * 16 * LDA];
#pragma unroll
            for (int i = 0; i < 4; ++i)
                acc[i][j] = __builtin_amdgcn_mfma_f32_16x16x32_f16(a_h[i], bb, acc[i][j], 0, 0, 0);
        }
    }

    // epilogue: softmax over W=64 (cols j*16+l15 within this wave's 64-col group)
#pragma unroll
    for (int i = 0; i < 4; ++i) {
#pragma unroll
        for (int r = 0; r < 4; ++r) {
            float v0 = acc[i][0][r], v1 = acc[i][1][r], v2 = acc[i][2][r], v3 = acc[i][3][r];
            float m = fmaxf(fmaxf(v0, v1), fmaxf(v2, v3));
#pragma unroll
            for (int off = 8; off > 0; off >>= 1) m = fmaxf(m, __shfl_xor(m, off, 16));
            float e0 = __expf(v0 - m), e1 = __expf(v1 - m), e2 = __expf(v2 - m), e3 = __expf(v3 - m);
            float sum = e0 + e1 + e2 + e3;
#pragma unroll
            for (int off = 8; off > 0; off >>= 1) sum += __shfl_xor(sum, off, 16);
            const float inv = 1.0f / sum;
            const int row = c0 + wm * 64 + i * 16 + quad * 4 + r;
            float* op = out + ((size_t)(b * CCH + row)) * NTOK + n0 + wn * 64 + l15;
            op[0]  = e0 * inv;
            op[16] = e1 * inv;
            op[32] = e2 * inv;
            op[48] = e3 * inv;
        }
    }
}

// ---------------------------------------------------------------------------
extern "C" void kernel_launch(void* const* d_in, const int* in_sizes, int n_in,
                              void* d_out, int out_size, void* d_ws, size_t ws_size,
                              hipStream_t stream) {
    const float* x_training = (const float*)d_in[0];  // kv
    const float* x_pre      = (const float*)d_in[1];  // q
    float* out = (float*)d_out;
    const size_t ES = (size_t)NB * CCH * CCH;         // 4.19M elems
    float* E0 = (float*)d_ws;                          // 16 MiB
    float* E1 = E0 + ES;                               // 16 MiB
    u16* ath = (u16*)(E1 + ES);                        // 8 MiB (fp16 att)

    energy_mfma<<<dim3(4, 4, 32), 256, 0, stream>>>(x_pre, x_training, E0);
    attn_softmax<<<dim3(NB * CCH), 256, 0, stream>>>(E0, E1, ath);
    out_mfma<<<dim3(NTOK / 128, CCH / 128, NB), 256, 0, stream>>>(ath, x_training, out);
}